// Round 2
// baseline (1164.047 us; speedup 1.0000x reference)
//
#include <hip/hip_runtime.h>

typedef unsigned short u16;
typedef unsigned int u32;

#define N_ATOM   50000
#define M_NBR    12
#define A_FEA    128
#define NBR_FEA  64
#define KDIM     320
#define CDIM     256
#define ROWS     600000
#define RPB      48          // rows per block (= 4 atoms)
#define NBLK     12500       // 600000 / 48
#define KC       10          // K chunks of 32
#define EPSV     1e-5f
#define A_PITCH  656         // (320+8) bf16 * 2B, padded row pitch in bytes

using frag  = __attribute__((ext_vector_type(8))) short;
using f32x4 = __attribute__((ext_vector_type(4))) float;

// ---- workspace layout (float offsets) ----
#define WS_SUM1      0
#define WS_SUMSQ1    256
#define WS_CNT       512
#define WS_SUM2      516
#define WS_SUMSQ2    644
#define WS_STATS_END 772
#define WS_SCALE1    1024
#define WS_SHIFT1    1280
#define WS_SCALE2    1536
#define WS_SHIFT2    1664
#define WS_NBR       2048                    // 50000*128 floats
#define WS_W_FOFF    (2048 + 6400000)        // bf16 swizzled W starts here (byte off = *4)

__device__ __forceinline__ u16 f2bf(float f) {
    union { float f; u32 u; } v; v.f = f;
    u32 r = v.u + 0x7fffu + ((v.u >> 16) & 1u);   // RNE
    return (u16)(r >> 16);
}
__device__ __forceinline__ float softplusf(float x) {
    return fmaxf(x, 0.f) + log1pf(__expf(-fabsf(x)));
}
__device__ __forceinline__ float sigmoidf(float x) {
    return 1.f / (1.f + __expf(-x));
}

// Swizzle W (320x256 row-major fp32) -> wsW[kk][n][32] fragment-major bf16
__global__ void swizzleW(const float* __restrict__ W, u16* __restrict__ wsW) {
    int g = blockIdx.x * 256 + threadIdx.x;
    if (g >= KDIM * CDIM) return;
    int k = g >> 8, n = g & 255;
    wsW[((k >> 5) * 256 + n) * 32 + (k & 31)] = f2bf(W[g]);
}

template <int PASS>
__global__ __launch_bounds__(256) void gemm_pass(
    const float* __restrict__ atom, const float* __restrict__ nbrf,
    const int* __restrict__ nbridx, const float* __restrict__ mask,
    const u16* __restrict__ wsW, float* __restrict__ ws)
{
    constexpr int SMEM_BYTES = (PASS == 1) ? (RPB * A_PITCH) : (RPB * CDIM * 4);
    __shared__ __align__(16) char smem[SMEM_BYTES];
    __shared__ float m_lds[RPB];
    __shared__ float red[(PASS == 2) ? 4 : 1][128];

    const int tid = threadIdx.x;
    const int w = tid >> 6, l = tid & 63, l15 = l & 15, l4 = l >> 4;
    const int blk = blockIdx.x;
    const int r0 = blk * RPB;
    const int wcol = w * 64;

    if (tid < RPB) m_lds[tid] = mask[r0 + tid];

    // ---- stage A-tile: 48 rows x 320 fp32 -> bf16 in LDS (pitch 656 B) ----
    // 80 chunks of 4 floats per row; 48*80 = 3840 chunks; 15 iters of 256
    #pragma unroll
    for (int it = 0; it < 15; ++it) {
        int idx = it * 256 + tid;
        int row = idx / 80;
        int c = idx - row * 80;
        int gr = r0 + row;
        int i = gr / 12;
        const float* src;
        if (c < 32)       src = atom + i * 128 + c * 4;
        else if (c < 64)  src = atom + nbridx[gr] * 128 + (c - 32) * 4;
        else              src = nbrf + gr * 64 + (c - 64) * 4;
        float4 v = *(const float4*)src;
        union { u16 u[4]; u32 d[2]; } o;
        o.u[0] = f2bf(v.x); o.u[1] = f2bf(v.y);
        o.u[2] = f2bf(v.z); o.u[3] = f2bf(v.w);
        *(u32*)(smem + row * A_PITCH + c * 8)     = o.d[0];
        *(u32*)(smem + row * A_PITCH + c * 8 + 4) = o.d[1];
    }
    __syncthreads();

    // ---- MFMA K-loop: 48x256 tile, wave w owns cols [64w,64w+64) ----
    f32x4 acc[3][4];
    #pragma unroll
    for (int rf = 0; rf < 3; rf++)
        #pragma unroll
        for (int cf = 0; cf < 4; cf++)
            acc[rf][cf] = (f32x4){0.f, 0.f, 0.f, 0.f};

    const char* Ab = (const char*)smem;
    #pragma unroll
    for (int kk = 0; kk < KC; ++kk) {
        frag a[3], b[4];
        #pragma unroll
        for (int rf = 0; rf < 3; rf++)
            a[rf] = *(const frag*)(Ab + (rf * 16 + l15) * A_PITCH + kk * 64 + l4 * 16);
        #pragma unroll
        for (int cf = 0; cf < 4; cf++)
            b[cf] = *(const frag*)(wsW + (kk * 256 + wcol + cf * 16 + l15) * 32 + l4 * 8);
        #pragma unroll
        for (int rf = 0; rf < 3; rf++)
            #pragma unroll
            for (int cf = 0; cf < 4; cf++)
                acc[rf][cf] = __builtin_amdgcn_mfma_f32_16x16x32_bf16(a[rf], b[cf], acc[rf][cf], 0, 0, 0);
    }

    if constexpr (PASS == 1) {
        // masked count (once per block, wave 0)
        if (w == 0) {
            float v = (l < RPB) ? m_lds[l] : 0.f;
            #pragma unroll
            for (int s = 1; s < 64; s <<= 1) v += __shfl_xor(v, s, 64);
            if (l == 0) atomicAdd(&ws[WS_CNT], v);
        }
        // masked column sums / sumsq
        #pragma unroll
        for (int cf = 0; cf < 4; cf++) {
            float s = 0.f, q = 0.f;
            #pragma unroll
            for (int rf = 0; rf < 3; rf++)
                #pragma unroll
                for (int rg = 0; rg < 4; rg++) {
                    int row = rf * 16 + l4 * 4 + rg;
                    float mv = m_lds[row];
                    float v = acc[rf][cf][rg];
                    s += mv * v; q += mv * v * v;
                }
            s += __shfl_xor(s, 16, 64); s += __shfl_xor(s, 32, 64);
            q += __shfl_xor(q, 16, 64); q += __shfl_xor(q, 32, 64);
            if (l4 == 0) {
                int col = wcol + cf * 16 + l15;
                atomicAdd(&ws[WS_SUM1 + col], s);
                atomicAdd(&ws[WS_SUMSQ1 + col], q);
            }
        }
    } else {
        // ---- apply BN1, write normalized tile to LDS (fp32, 48x256) ----
        __syncthreads();   // all A-tile reads done before overwrite
        float* g = (float*)smem;
        #pragma unroll
        for (int cf = 0; cf < 4; cf++) {
            int col = wcol + cf * 16 + l15;
            float sc = ws[WS_SCALE1 + col];
            float sh = ws[WS_SHIFT1 + col];
            #pragma unroll
            for (int rf = 0; rf < 3; rf++)
                #pragma unroll
                for (int rg = 0; rg < 4; rg++) {
                    int row = rf * 16 + l4 * 4 + rg;
                    g[row * 256 + col] = acc[rf][cf][rg] * sc + sh;
                }
        }
        __syncthreads();
        // ---- gated activation + reduce over M=12 -> nbr_sumed (4 atoms/block) ----
        int h = tid >> 7;       // 0,1
        int c = tid & 127;
        float ns0 = 0.f, ns1 = 0.f;
        #pragma unroll
        for (int la2 = 0; la2 < 2; la2++) {
            int la = h * 2 + la2;
            float a_ns = 0.f;
            #pragma unroll
            for (int j = 0; j < 12; j++) {
                int row = la * 12 + j;
                float f = g[row * 256 + c];
                float k = g[row * 256 + 128 + c];
                a_ns += m_lds[row] * sigmoidf(f) * softplusf(k);
            }
            ws[WS_NBR + (blk * 4 + la) * 128 + c] = a_ns;
            if (la2 == 0) ns0 = a_ns; else ns1 = a_ns;
        }
        red[h][c]     = ns0 + ns1;
        red[2 + h][c] = ns0 * ns0 + ns1 * ns1;
        __syncthreads();
        if (tid < 128) {
            atomicAdd(&ws[WS_SUM2 + tid],   red[0][tid] + red[1][tid]);
            atomicAdd(&ws[WS_SUMSQ2 + tid], red[2][tid] + red[3][tid]);
        }
    }
}

__global__ void finalize1(float* __restrict__ ws, const float* __restrict__ g1, const float* __restrict__ b1) {
    int c = threadIdx.x;  // 256
    float cnt = ws[WS_CNT];
    float mean = ws[WS_SUM1 + c] / cnt;
    float var  = ws[WS_SUMSQ1 + c] / cnt - mean * mean;
    float sc = g1[c] * rsqrtf(var + EPSV);
    ws[WS_SCALE1 + c] = sc;
    ws[WS_SHIFT1 + c] = b1[c] - mean * sc;
}

__global__ void finalize2(float* __restrict__ ws, const float* __restrict__ g2, const float* __restrict__ b2) {
    int c = threadIdx.x;  // 128
    float inv = 1.f / (float)N_ATOM;
    float mean = ws[WS_SUM2 + c] * inv;
    float var  = ws[WS_SUMSQ2 + c] * inv - mean * mean;
    float sc = g2[c] * rsqrtf(var + EPSV);
    ws[WS_SCALE2 + c] = sc;
    ws[WS_SHIFT2 + c] = b2[c] - mean * sc;
}

__global__ __launch_bounds__(256) void out_kernel(
    const float* __restrict__ atom, const float* __restrict__ ws, float* __restrict__ out)
{
    int g = blockIdx.x * 256 + threadIdx.x;
    if (g >= N_ATOM * 32) return;
    int i = g >> 5, c4 = (g & 31) * 4;
    float4 av = *(const float4*)(atom + i * 128 + c4);
    float4 nv = *(const float4*)(ws + WS_NBR + i * 128 + c4);
    float4 sc = *(const float4*)(ws + WS_SCALE2 + c4);
    float4 sh = *(const float4*)(ws + WS_SHIFT2 + c4);
    float4 ov;
    ov.x = softplusf(av.x + nv.x * sc.x + sh.x);
    ov.y = softplusf(av.y + nv.y * sc.y + sh.y);
    ov.z = softplusf(av.z + nv.z * sc.z + sh.z);
    ov.w = softplusf(av.w + nv.w * sc.w + sh.w);
    *(float4*)(out + i * 128 + c4) = ov;
}

extern "C" void kernel_launch(void* const* d_in, const int* in_sizes, int n_in,
                              void* d_out, int out_size, void* d_ws, size_t ws_size,
                              hipStream_t stream) {
    (void)in_sizes; (void)n_in; (void)out_size; (void)ws_size;
    const float* atom = (const float*)d_in[0];
    const float* nbrf = (const float*)d_in[1];
    const int*   nidx = (const int*)d_in[2];
    const float* mask = (const float*)d_in[3];
    const float* W    = (const float*)d_in[4];
    // d_in[5] = b_fc: zeros AND cancels exactly through BN1 for masked rows; unused
    const float* g1 = (const float*)d_in[6];
    const float* b1 = (const float*)d_in[7];
    const float* g2 = (const float*)d_in[8];
    const float* b2 = (const float*)d_in[9];
    float* ws  = (float*)d_ws;
    u16*  wsW  = (u16*)((char*)d_ws + (size_t)WS_W_FOFF * 4);
    float* out = (float*)d_out;

    hipMemsetAsync(d_ws, 0, WS_STATS_END * 4, stream);
    swizzleW<<<(KDIM * CDIM + 255) / 256, 256, 0, stream>>>(W, wsW);
    gemm_pass<1><<<NBLK, 256, 0, stream>>>(atom, nbrf, nidx, mask, wsW, ws);
    finalize1<<<1, 256, 0, stream>>>(ws, g1, b1);
    gemm_pass<2><<<NBLK, 256, 0, stream>>>(atom, nbrf, nidx, mask, wsW, ws);
    finalize2<<<1, 128, 0, stream>>>(ws, g2, b2);
    out_kernel<<<(N_ATOM * 32 + 255) / 256, 256, 0, stream>>>(atom, ws, out);
}

// Round 3
// 1104.001 us; speedup vs baseline: 1.0544x; 1.0544x over previous
//
#include <hip/hip_runtime.h>

typedef unsigned short u16;
typedef unsigned int u32;

#define N_ATOM   50000
#define M_NBR    12
#define A_FEA    128
#define NBR_FEA  64
#define KDIM     320
#define CDIM     256
#define ROWS     600000
#define RPB      48          // rows per block (= 4 atoms)
#define NBLK     12500       // 600000 / 48
#define KC       10          // K chunks of 32
#define EPSV     1e-5f
#define A_PITCH  656         // (320+8) bf16 * 2B, padded row pitch in bytes

using frag  = __attribute__((ext_vector_type(8))) short;
using f32x4 = __attribute__((ext_vector_type(4))) float;

// ---- workspace layout (float offsets) ----
#define WS_SUM1      0
#define WS_SUMSQ1    256
#define WS_CNT       512
#define WS_SUM2      516
#define WS_SUMSQ2    644
#define WS_STATS_END 772
#define WS_SCALE1    1024
#define WS_SHIFT1    1280
#define WS_SCALE2    1536
#define WS_SHIFT2    1664
#define WS_NBR       2048                    // 50000*128 floats
#define WS_W_FOFF    (2048 + 6400000)        // bf16 swizzled W starts here (byte off = *4)

__device__ __forceinline__ u16 f2bf(float f) {
    union { float f; u32 u; } v; v.f = f;
    u32 r = v.u + 0x7fffu + ((v.u >> 16) & 1u);   // RNE
    return (u16)(r >> 16);
}
__device__ __forceinline__ float bf2f(u16 u) {
    union { u32 i; float f; } v; v.i = ((u32)u) << 16; return v.f;
}
__device__ __forceinline__ float softplusf(float x) {
    return fmaxf(x, 0.f) + log1pf(__expf(-fabsf(x)));
}
__device__ __forceinline__ float sigmoidf(float x) {
    return 1.f / (1.f + __expf(-x));
}

// Swizzle W (320x256 row-major fp32) -> wsW[kk][n][32] fragment-major bf16
__global__ void swizzleW(const float* __restrict__ W, u16* __restrict__ wsW) {
    int g = blockIdx.x * 256 + threadIdx.x;
    if (g >= KDIM * CDIM) return;
    int k = g >> 8, n = g & 255;
    wsW[((k >> 5) * 256 + n) * 32 + (k & 31)] = f2bf(W[g]);
}

template <int PASS>
__global__ __launch_bounds__(256, 3) void gemm_pass(
    const float* __restrict__ atom, const float* __restrict__ nbrf,
    const int* __restrict__ nbridx, const float* __restrict__ mask,
    const u16* __restrict__ wsW, float* __restrict__ ws)
{
    // A-tile (bf16, 48x328 pitch) in pass 1/2; pass-2 G tile (bf16 48x256) reuses it
    __shared__ __align__(16) char smem[RPB * A_PITCH];
    __shared__ float m_lds[RPB];
    __shared__ int   idx_lds[RPB];
    __shared__ float red[4][128];

    const int tid = threadIdx.x;
    const int w = tid >> 6, l = tid & 63, l15 = l & 15, l4 = l >> 4;
    const int blk = blockIdx.x;
    const int r0 = blk * RPB;
    const int wcol = w * 64;

    if (tid < RPB) {
        m_lds[tid] = mask[r0 + tid];
        idx_lds[tid] = nbridx[r0 + tid];
    }

    // ---- prefetch B fragments for kk=0..4 (overlaps A staging; L2-resident W) ----
    frag b_pre[5][4];
    #pragma unroll
    for (int s = 0; s < 5; ++s)
        #pragma unroll
        for (int cf = 0; cf < 4; ++cf)
            b_pre[s][cf] = *(const frag*)(wsW + ((size_t)(s * 256 + wcol + cf * 16 + l15)) * 32 + l4 * 8);

    __syncthreads();   // idx_lds/m_lds visible

    // ---- stage A-tile: 48 rows x 320 fp32 -> bf16 in LDS (pitch 656 B) ----
    // 80 chunks of 4 floats per row; 48*80 = 3840 chunks; 15 iters of 256
    #pragma unroll
    for (int it = 0; it < 15; ++it) {
        int idx = it * 256 + tid;
        int row = idx / 80;
        int c = idx - row * 80;
        int gr = r0 + row;
        const float* src;
        if (c < 32)       src = atom + (size_t)(gr / 12) * 128 + c * 4;
        else if (c < 64)  src = atom + (size_t)idx_lds[row] * 128 + (c - 32) * 4;
        else              src = nbrf + (size_t)gr * 64 + (c - 64) * 4;
        float4 v = *(const float4*)src;
        union { u16 u[4]; u32 d[2]; } o;
        o.u[0] = f2bf(v.x); o.u[1] = f2bf(v.y);
        o.u[2] = f2bf(v.z); o.u[3] = f2bf(v.w);
        *(u32*)(smem + row * A_PITCH + c * 8)     = o.d[0];
        *(u32*)(smem + row * A_PITCH + c * 8 + 4) = o.d[1];
    }
    __syncthreads();

    // ---- MFMA K-loop: 48x256 tile, wave w owns cols [64w,64w+64) ----
    f32x4 acc[3][4];
    #pragma unroll
    for (int rf = 0; rf < 3; rf++)
        #pragma unroll
        for (int cf = 0; cf < 4; cf++)
            acc[rf][cf] = (f32x4){0.f, 0.f, 0.f, 0.f};

    const char* Ab = (const char*)smem;
    #pragma unroll
    for (int kk = 0; kk < KC; ++kk) {
        const int s = kk % 5;
        frag b0 = b_pre[s][0], b1 = b_pre[s][1], b2 = b_pre[s][2], b3 = b_pre[s][3];
        if (kk < 5) {   // refill slot s for kk+5, ~5 iterations of lead time
            #pragma unroll
            for (int cf = 0; cf < 4; ++cf)
                b_pre[s][cf] = *(const frag*)(wsW + ((size_t)((kk + 5) * 256 + wcol + cf * 16 + l15)) * 32 + l4 * 8);
        }
        frag a[3];
        #pragma unroll
        for (int rf = 0; rf < 3; rf++)
            a[rf] = *(const frag*)(Ab + (rf * 16 + l15) * A_PITCH + kk * 64 + l4 * 16);
        #pragma unroll
        for (int rf = 0; rf < 3; rf++) {
            acc[rf][0] = __builtin_amdgcn_mfma_f32_16x16x32_bf16(a[rf], b0, acc[rf][0], 0, 0, 0);
            acc[rf][1] = __builtin_amdgcn_mfma_f32_16x16x32_bf16(a[rf], b1, acc[rf][1], 0, 0, 0);
            acc[rf][2] = __builtin_amdgcn_mfma_f32_16x16x32_bf16(a[rf], b2, acc[rf][2], 0, 0, 0);
            acc[rf][3] = __builtin_amdgcn_mfma_f32_16x16x32_bf16(a[rf], b3, acc[rf][3], 0, 0, 0);
        }
    }

    if constexpr (PASS == 1) {
        // masked count (once per block, wave 0)
        if (w == 0) {
            float v = (l < RPB) ? m_lds[l] : 0.f;
            #pragma unroll
            for (int s = 1; s < 64; s <<= 1) v += __shfl_xor(v, s, 64);
            if (l == 0) atomicAdd(&ws[WS_CNT], v);
        }
        // masked column sums / sumsq
        #pragma unroll
        for (int cf = 0; cf < 4; cf++) {
            float s = 0.f, q = 0.f;
            #pragma unroll
            for (int rf = 0; rf < 3; rf++)
                #pragma unroll
                for (int rg = 0; rg < 4; rg++) {
                    int row = rf * 16 + l4 * 4 + rg;
                    float mv = m_lds[row];
                    float v = acc[rf][cf][rg];
                    s += mv * v; q += mv * v * v;
                }
            s += __shfl_xor(s, 16, 64); s += __shfl_xor(s, 32, 64);
            q += __shfl_xor(q, 16, 64); q += __shfl_xor(q, 32, 64);
            if (l4 == 0) {
                int col = wcol + cf * 16 + l15;
                atomicAdd(&ws[WS_SUM1 + col], s);
                atomicAdd(&ws[WS_SUMSQ1 + col], q);
            }
        }
    } else {
        // ---- apply BN1, write normalized tile to LDS as bf16 (48x256) ----
        __syncthreads();   // all A-tile reads done before overwrite
        u16* g16 = (u16*)smem;
        #pragma unroll
        for (int cf = 0; cf < 4; cf++) {
            int col = wcol + cf * 16 + l15;
            float sc = ws[WS_SCALE1 + col];
            float sh = ws[WS_SHIFT1 + col];
            #pragma unroll
            for (int rf = 0; rf < 3; rf++)
                #pragma unroll
                for (int rg = 0; rg < 4; rg++) {
                    int row = rf * 16 + l4 * 4 + rg;
                    g16[row * 256 + col] = f2bf(acc[rf][cf][rg] * sc + sh);
                }
        }
        __syncthreads();
        // ---- gated activation + reduce over M=12 -> nbr_sumed (4 atoms/block) ----
        int h = tid >> 7;       // 0,1
        int c = tid & 127;
        float ns0 = 0.f, ns1 = 0.f;
        #pragma unroll
        for (int la2 = 0; la2 < 2; la2++) {
            int la = h * 2 + la2;
            float a_ns = 0.f;
            #pragma unroll
            for (int j = 0; j < 12; j++) {
                int row = la * 12 + j;
                float f = bf2f(g16[row * 256 + c]);
                float k = bf2f(g16[row * 256 + 128 + c]);
                a_ns += m_lds[row] * sigmoidf(f) * softplusf(k);
            }
            ws[WS_NBR + (blk * 4 + la) * 128 + c] = a_ns;
            if (la2 == 0) ns0 = a_ns; else ns1 = a_ns;
        }
        red[h][c]     = ns0 + ns1;
        red[2 + h][c] = ns0 * ns0 + ns1 * ns1;
        __syncthreads();
        if (tid < 128) {
            atomicAdd(&ws[WS_SUM2 + tid],   red[0][tid] + red[1][tid]);
            atomicAdd(&ws[WS_SUMSQ2 + tid], red[2][tid] + red[3][tid]);
        }
    }
}

__global__ void finalize1(float* __restrict__ ws, const float* __restrict__ g1, const float* __restrict__ b1) {
    int c = threadIdx.x;  // 256
    float cnt = ws[WS_CNT];
    float mean = ws[WS_SUM1 + c] / cnt;
    float var  = ws[WS_SUMSQ1 + c] / cnt - mean * mean;
    float sc = g1[c] * rsqrtf(var + EPSV);
    ws[WS_SCALE1 + c] = sc;
    ws[WS_SHIFT1 + c] = b1[c] - mean * sc;
}

__global__ void finalize2(float* __restrict__ ws, const float* __restrict__ g2, const float* __restrict__ b2) {
    int c = threadIdx.x;  // 128
    float inv = 1.f / (float)N_ATOM;
    float mean = ws[WS_SUM2 + c] * inv;
    float var  = ws[WS_SUMSQ2 + c] * inv - mean * mean;
    float sc = g2[c] * rsqrtf(var + EPSV);
    ws[WS_SCALE2 + c] = sc;
    ws[WS_SHIFT2 + c] = b2[c] - mean * sc;
}

__global__ __launch_bounds__(256) void out_kernel(
    const float* __restrict__ atom, const float* __restrict__ ws, float* __restrict__ out)
{
    int g = blockIdx.x * 256 + threadIdx.x;
    if (g >= N_ATOM * 32) return;
    int i = g >> 5, c4 = (g & 31) * 4;
    float4 av = *(const float4*)(atom + i * 128 + c4);
    float4 nv = *(const float4*)(ws + WS_NBR + i * 128 + c4);
    float4 sc = *(const float4*)(ws + WS_SCALE2 + c4);
    float4 sh = *(const float4*)(ws + WS_SHIFT2 + c4);
    float4 ov;
    ov.x = softplusf(av.x + nv.x * sc.x + sh.x);
    ov.y = softplusf(av.y + nv.y * sc.y + sh.y);
    ov.z = softplusf(av.z + nv.z * sc.z + sh.z);
    ov.w = softplusf(av.w + nv.w * sc.w + sh.w);
    *(float4*)(out + i * 128 + c4) = ov;
}

extern "C" void kernel_launch(void* const* d_in, const int* in_sizes, int n_in,
                              void* d_out, int out_size, void* d_ws, size_t ws_size,
                              hipStream_t stream) {
    (void)in_sizes; (void)n_in; (void)out_size; (void)ws_size;
    const float* atom = (const float*)d_in[0];
    const float* nbrf = (const float*)d_in[1];
    const int*   nidx = (const int*)d_in[2];
    const float* mask = (const float*)d_in[3];
    const float* W    = (const float*)d_in[4];
    // d_in[5] = b_fc: zeros AND cancels exactly through BN1 for masked rows; unused
    const float* g1 = (const float*)d_in[6];
    const float* b1 = (const float*)d_in[7];
    const float* g2 = (const float*)d_in[8];
    const float* b2 = (const float*)d_in[9];
    float* ws  = (float*)d_ws;
    u16*  wsW  = (u16*)((char*)d_ws + (size_t)WS_W_FOFF * 4);
    float* out = (float*)d_out;

    hipMemsetAsync(d_ws, 0, WS_STATS_END * 4, stream);
    swizzleW<<<(KDIM * CDIM + 255) / 256, 256, 0, stream>>>(W, wsW);
    gemm_pass<1><<<NBLK, 256, 0, stream>>>(atom, nbrf, nidx, mask, wsW, ws);
    finalize1<<<1, 256, 0, stream>>>(ws, g1, b1);
    gemm_pass<2><<<NBLK, 256, 0, stream>>>(atom, nbrf, nidx, mask, wsW, ws);
    finalize2<<<1, 128, 0, stream>>>(ws, g2, b2);
    out_kernel<<<(N_ATOM * 32 + 255) / 256, 256, 0, stream>>>(atom, ws, out);
}

// Round 4
// 873.445 us; speedup vs baseline: 1.3327x; 1.2640x over previous
//
#include <hip/hip_runtime.h>

typedef unsigned short u16;
typedef unsigned int u32;

#define N_ATOM   50000
#define M_NBR    12
#define A_FEA    128
#define NBR_FEA  64
#define KDIM     320
#define CDIM     256
#define ROWS     600000
#define RPB      48          // rows per block (= 4 atoms)
#define NBLK     12500       // 600000 / 48
#define KC       10          // K chunks of 32
#define EPSV     1e-5f
#define A_PITCH  656         // (320+8) bf16 * 2B, padded row pitch in bytes

using frag  = __attribute__((ext_vector_type(8))) short;
using f32x4 = __attribute__((ext_vector_type(4))) float;

// ---- workspace layout (float offsets) ----
#define WS_SUM1      0        // 256 (red1 adds here)
#define WS_SUMSQ1    256      // 256 (contiguous with SUM1)
#define WS_CNT       512
#define WS_SUM2      516      // 128
#define WS_SUMSQ2    644      // 128 (contiguous with SUM2)
#define WS_STATS_END 772
#define WS_SCALE1    1024
#define WS_SHIFT1    1280
#define WS_SCALE2    1536
#define WS_SHIFT2    1664
#define WS_NBR       2048                      // 50000*128 floats
#define WS_W_FOFF    (2048 + 6400000)          // swizzled W: 81920 u16 = 40960 floats
#define WS_P_FOFF    (2048 + 6400000 + 40960)  // per-block partials: pass1 12500*512, pass2 12500*256 (shared)

__device__ __forceinline__ u16 f2bf(float f) {
    union { float f; u32 u; } v; v.f = f;
    u32 r = v.u + 0x7fffu + ((v.u >> 16) & 1u);   // RNE
    return (u16)(r >> 16);
}
__device__ __forceinline__ float bf2f(u16 u) {
    union { u32 i; float f; } v; v.i = ((u32)u) << 16; return v.f;
}
__device__ __forceinline__ float softplusf(float x) {
    return fmaxf(x, 0.f) + log1pf(__expf(-fabsf(x)));
}
__device__ __forceinline__ float sigmoidf(float x) {
    return 1.f / (1.f + __expf(-x));
}

// Swizzle W (320x256 row-major fp32) -> wsW[kk][n][32] fragment-major bf16
__global__ void swizzleW(const float* __restrict__ W, u16* __restrict__ wsW) {
    int g = blockIdx.x * 256 + threadIdx.x;
    if (g >= KDIM * CDIM) return;
    int k = g >> 8, n = g & 255;
    wsW[((k >> 5) * 256 + n) * 32 + (k & 31)] = f2bf(W[g]);
}

// sum(mask) -> ws[WS_CNT]; 600000 = 37500 * 16, each thread does 4 float4
__global__ __launch_bounds__(256) void mask_cnt(const float* __restrict__ mask, float* __restrict__ ws) {
    int t = blockIdx.x * 256 + threadIdx.x;
    float s = 0.f;
    if (t < 37500) {
        const float* p = mask + (size_t)t * 16;
        #pragma unroll
        for (int i = 0; i < 4; i++) {
            float4 v = *(const float4*)(p + i * 4);
            s += (v.x + v.y) + (v.z + v.w);
        }
    }
    #pragma unroll
    for (int d = 1; d < 64; d <<= 1) s += __shfl_xor(s, d, 64);
    __shared__ float r[4];
    int l = threadIdx.x & 63, w = threadIdx.x >> 6;
    if (l == 0) r[w] = s;
    __syncthreads();
    if (threadIdx.x == 0) atomicAdd(&ws[WS_CNT], r[0] + r[1] + r[2] + r[3]);
}

template <int PASS>
__global__ __launch_bounds__(256, 3) void gemm_pass(
    const float* __restrict__ atom, const float* __restrict__ nbrf,
    const int* __restrict__ nbridx, const float* __restrict__ mask,
    const u16* __restrict__ wsW, float* __restrict__ ws)
{
    // A-tile (bf16, 48x328 pitch); pass-2 G tile (bf16 48x256) reuses it
    __shared__ __align__(16) char smem[RPB * A_PITCH];
    __shared__ float m_lds[RPB];
    __shared__ int   idx_lds[RPB];
    __shared__ float red[4][128];

    const int tid = threadIdx.x;
    const int w = tid >> 6, l = tid & 63, l15 = l & 15, l4 = l >> 4;
    const int blk = blockIdx.x;
    const int r0 = blk * RPB;
    const int wcol = w * 64;
    float* __restrict__ P = ws + WS_P_FOFF;

    if (tid < RPB) {
        m_lds[tid] = mask[r0 + tid];
        idx_lds[tid] = nbridx[r0 + tid];
    }

    // ---- prefetch B fragments for kk=0..4 ----
    frag b_pre[5][4];
    #pragma unroll
    for (int s = 0; s < 5; ++s)
        #pragma unroll
        for (int cf = 0; cf < 4; ++cf)
            b_pre[s][cf] = *(const frag*)(wsW + ((size_t)(s * 256 + wcol + cf * 16 + l15)) * 32 + l4 * 8);

    __syncthreads();   // idx_lds/m_lds visible

    // ---- stage A-tile: 48 rows x 320 fp32 -> bf16 in LDS (pitch 656 B) ----
    #pragma unroll
    for (int it = 0; it < 15; ++it) {
        int idx = it * 256 + tid;
        int row = idx / 80;
        int c = idx - row * 80;
        int gr = r0 + row;
        const float* src;
        if (c < 32)       src = atom + (size_t)(gr / 12) * 128 + c * 4;
        else if (c < 64)  src = atom + (size_t)idx_lds[row] * 128 + (c - 32) * 4;
        else              src = nbrf + (size_t)gr * 64 + (c - 64) * 4;
        float4 v = *(const float4*)src;
        union { u16 u[4]; u32 d[2]; } o;
        o.u[0] = f2bf(v.x); o.u[1] = f2bf(v.y);
        o.u[2] = f2bf(v.z); o.u[3] = f2bf(v.w);
        *(u32*)(smem + row * A_PITCH + c * 8)     = o.d[0];
        *(u32*)(smem + row * A_PITCH + c * 8 + 4) = o.d[1];
    }
    __syncthreads();

    // ---- MFMA K-loop: 48x256 tile, wave w owns cols [64w,64w+64) ----
    f32x4 acc[3][4];
    #pragma unroll
    for (int rf = 0; rf < 3; rf++)
        #pragma unroll
        for (int cf = 0; cf < 4; cf++)
            acc[rf][cf] = (f32x4){0.f, 0.f, 0.f, 0.f};

    const char* Ab = (const char*)smem;
    #pragma unroll
    for (int kk = 0; kk < KC; ++kk) {
        const int s = kk % 5;
        frag b0 = b_pre[s][0], b1 = b_pre[s][1], b2 = b_pre[s][2], b3 = b_pre[s][3];
        if (kk < 5) {
            #pragma unroll
            for (int cf = 0; cf < 4; ++cf)
                b_pre[s][cf] = *(const frag*)(wsW + ((size_t)((kk + 5) * 256 + wcol + cf * 16 + l15)) * 32 + l4 * 8);
        }
        frag a[3];
        #pragma unroll
        for (int rf = 0; rf < 3; rf++)
            a[rf] = *(const frag*)(Ab + (rf * 16 + l15) * A_PITCH + kk * 64 + l4 * 16);
        #pragma unroll
        for (int rf = 0; rf < 3; rf++) {
            acc[rf][0] = __builtin_amdgcn_mfma_f32_16x16x32_bf16(a[rf], b0, acc[rf][0], 0, 0, 0);
            acc[rf][1] = __builtin_amdgcn_mfma_f32_16x16x32_bf16(a[rf], b1, acc[rf][1], 0, 0, 0);
            acc[rf][2] = __builtin_amdgcn_mfma_f32_16x16x32_bf16(a[rf], b2, acc[rf][2], 0, 0, 0);
            acc[rf][3] = __builtin_amdgcn_mfma_f32_16x16x32_bf16(a[rf], b3, acc[rf][3], 0, 0, 0);
        }
    }

    if constexpr (PASS == 1) {
        // masked column sums / sumsq -> per-block partials (NO global atomics)
        #pragma unroll
        for (int cf = 0; cf < 4; cf++) {
            float s = 0.f, q = 0.f;
            #pragma unroll
            for (int rf = 0; rf < 3; rf++)
                #pragma unroll
                for (int rg = 0; rg < 4; rg++) {
                    int row = rf * 16 + l4 * 4 + rg;
                    float mv = m_lds[row];
                    float v = acc[rf][cf][rg];
                    s += mv * v; q += mv * v * v;
                }
            s += __shfl_xor(s, 16, 64); s += __shfl_xor(s, 32, 64);
            q += __shfl_xor(q, 16, 64); q += __shfl_xor(q, 32, 64);
            if (l4 == 0) {
                int col = wcol + cf * 16 + l15;
                P[(size_t)blk * 512 + col]       = s;
                P[(size_t)blk * 512 + 256 + col] = q;
            }
        }
    } else {
        // ---- apply BN1, write normalized tile to LDS as bf16 (48x256) ----
        __syncthreads();   // all A-tile reads done before overwrite
        u16* g16 = (u16*)smem;
        #pragma unroll
        for (int cf = 0; cf < 4; cf++) {
            int col = wcol + cf * 16 + l15;
            float sc = ws[WS_SCALE1 + col];
            float sh = ws[WS_SHIFT1 + col];
            #pragma unroll
            for (int rf = 0; rf < 3; rf++)
                #pragma unroll
                for (int rg = 0; rg < 4; rg++) {
                    int row = rf * 16 + l4 * 4 + rg;
                    g16[row * 256 + col] = f2bf(acc[rf][cf][rg] * sc + sh);
                }
        }
        __syncthreads();
        // ---- gated activation + reduce over M=12 -> nbr_sumed (4 atoms/block) ----
        int h = tid >> 7;       // 0,1
        int c = tid & 127;
        float ns0 = 0.f, ns1 = 0.f;
        #pragma unroll
        for (int la2 = 0; la2 < 2; la2++) {
            int la = h * 2 + la2;
            float a_ns = 0.f;
            #pragma unroll
            for (int j = 0; j < 12; j++) {
                int row = la * 12 + j;
                float f = bf2f(g16[row * 256 + c]);
                float k = bf2f(g16[row * 256 + 128 + c]);
                a_ns += m_lds[row] * sigmoidf(f) * softplusf(k);
            }
            ws[WS_NBR + (blk * 4 + la) * 128 + c] = a_ns;
            if (la2 == 0) ns0 = a_ns; else ns1 = a_ns;
        }
        red[h][c]     = ns0 + ns1;
        red[2 + h][c] = ns0 * ns0 + ns1 * ns1;
        __syncthreads();
        if (tid < 128) {
            P[(size_t)blk * 256 + tid]       = red[0][tid] + red[1][tid];
            P[(size_t)blk * 256 + 128 + tid] = red[2][tid] + red[3][tid];
        }
    }
}

// reduce P1[12500][512] over blocks -> ws[WS_SUM1..WS_SUMSQ1] (contiguous 512)
// grid 250: blockIdx&1 = column half, blockIdx>>1 = strip of 100 block-rows
__global__ __launch_bounds__(256) void red1(const float* __restrict__ ws_ro, float* __restrict__ ws) {
    const float* P = ws_ro + WS_P_FOFF;
    int c = (blockIdx.x & 1) * 256 + threadIdx.x;
    int s = blockIdx.x >> 1;
    const float* p = P + (size_t)s * 100 * 512 + c;
    float a = 0.f;
    #pragma unroll 4
    for (int r = 0; r < 100; r++) a += p[(size_t)r * 512];
    atomicAdd(&ws[WS_SUM1 + c], a);   // 125 adds per address
}

// reduce P2[12500][256] over blocks -> ws[WS_SUM2..WS_SUMSQ2] (contiguous 256)
__global__ __launch_bounds__(256) void red2(const float* __restrict__ ws_ro, float* __restrict__ ws) {
    const float* P = ws_ro + WS_P_FOFF;
    int s = blockIdx.x;   // 125 strips of 100
    const float* p = P + (size_t)s * 100 * 256 + threadIdx.x;
    float a = 0.f;
    #pragma unroll 4
    for (int r = 0; r < 100; r++) a += p[(size_t)r * 256];
    atomicAdd(&ws[WS_SUM2 + threadIdx.x], a);
}

__global__ void finalize1(float* __restrict__ ws, const float* __restrict__ g1, const float* __restrict__ b1) {
    int c = threadIdx.x;  // 256
    float cnt = ws[WS_CNT];
    float mean = ws[WS_SUM1 + c] / cnt;
    float var  = ws[WS_SUMSQ1 + c] / cnt - mean * mean;
    float sc = g1[c] * rsqrtf(var + EPSV);
    ws[WS_SCALE1 + c] = sc;
    ws[WS_SHIFT1 + c] = b1[c] - mean * sc;
}

__global__ void finalize2(float* __restrict__ ws, const float* __restrict__ g2, const float* __restrict__ b2) {
    int c = threadIdx.x;  // 128
    float inv = 1.f / (float)N_ATOM;
    float mean = ws[WS_SUM2 + c] * inv;
    float var  = ws[WS_SUMSQ2 + c] * inv - mean * mean;
    float sc = g2[c] * rsqrtf(var + EPSV);
    ws[WS_SCALE2 + c] = sc;
    ws[WS_SHIFT2 + c] = b2[c] - mean * sc;
}

__global__ __launch_bounds__(256) void out_kernel(
    const float* __restrict__ atom, const float* __restrict__ ws, float* __restrict__ out)
{
    int g = blockIdx.x * 256 + threadIdx.x;
    if (g >= N_ATOM * 32) return;
    int i = g >> 5, c4 = (g & 31) * 4;
    float4 av = *(const float4*)(atom + i * 128 + c4);
    float4 nv = *(const float4*)(ws + WS_NBR + i * 128 + c4);
    float4 sc = *(const float4*)(ws + WS_SCALE2 + c4);
    float4 sh = *(const float4*)(ws + WS_SHIFT2 + c4);
    float4 ov;
    ov.x = softplusf(av.x + nv.x * sc.x + sh.x);
    ov.y = softplusf(av.y + nv.y * sc.y + sh.y);
    ov.z = softplusf(av.z + nv.z * sc.z + sh.z);
    ov.w = softplusf(av.w + nv.w * sc.w + sh.w);
    *(float4*)(out + i * 128 + c4) = ov;
}

extern "C" void kernel_launch(void* const* d_in, const int* in_sizes, int n_in,
                              void* d_out, int out_size, void* d_ws, size_t ws_size,
                              hipStream_t stream) {
    (void)in_sizes; (void)n_in; (void)out_size; (void)ws_size;
    const float* atom = (const float*)d_in[0];
    const float* nbrf = (const float*)d_in[1];
    const int*   nidx = (const int*)d_in[2];
    const float* mask = (const float*)d_in[3];
    const float* W    = (const float*)d_in[4];
    // d_in[5] = b_fc: zeros AND cancels exactly through BN1 for masked rows; unused
    const float* g1 = (const float*)d_in[6];
    const float* b1 = (const float*)d_in[7];
    const float* g2 = (const float*)d_in[8];
    const float* b2 = (const float*)d_in[9];
    float* ws  = (float*)d_ws;
    u16*  wsW  = (u16*)((char*)d_ws + (size_t)WS_W_FOFF * 4);
    float* out = (float*)d_out;

    hipMemsetAsync(d_ws, 0, WS_STATS_END * 4, stream);
    swizzleW<<<(KDIM * CDIM + 255) / 256, 256, 0, stream>>>(W, wsW);
    mask_cnt<<<147, 256, 0, stream>>>(mask, ws);
    gemm_pass<1><<<NBLK, 256, 0, stream>>>(atom, nbrf, nidx, mask, wsW, ws);
    red1<<<250, 256, 0, stream>>>(ws, ws);
    finalize1<<<1, 256, 0, stream>>>(ws, g1, b1);
    gemm_pass<2><<<NBLK, 256, 0, stream>>>(atom, nbrf, nidx, mask, wsW, ws);
    red2<<<125, 256, 0, stream>>>(ws, ws);
    finalize2<<<1, 128, 0, stream>>>(ws, g2, b2);
    out_kernel<<<(N_ATOM * 32 + 255) / 256, 256, 0, stream>>>(atom, ws, out);
}

// Round 5
// 670.029 us; speedup vs baseline: 1.7373x; 1.3036x over previous
//
#include <hip/hip_runtime.h>

typedef unsigned short u16;
typedef unsigned int u32;

#define N_ATOM   50000
#define M_NBR    12
#define A_FEA    128
#define NBR_FEA  64
#define KDIM     320
#define CDIM     256
#define ROWS     600000
#define RPB      48          // rows per block (= 4 atoms)
#define NBLK     12500       // 600000 / 48
#define KC       10          // K chunks of 32
#define EPSV     1e-5f
#define A_PITCH  656         // (320+8) bf16 * 2B, padded row pitch in bytes

using frag  = __attribute__((ext_vector_type(8))) short;
using f32x4 = __attribute__((ext_vector_type(4))) float;

// ---- workspace layout (float offsets) ----
#define WS_SUM1      0        // 256 (red1 adds here)
#define WS_SUMSQ1    256      // 256 (contiguous with SUM1)
#define WS_CNT       512
#define WS_SUM2      516      // 128
#define WS_SUMSQ2    644      // 128 (contiguous with SUM2)
#define WS_STATS_END 772
#define WS_SCALE1    1024
#define WS_SHIFT1    1280
#define WS_SCALE2    1536
#define WS_SHIFT2    1664
#define WS_NBR       2048                      // 50000*128 floats
#define WS_W_FOFF    (2048 + 6400000)          // swizzled W: 81920 u16 = 40960 floats
#define WS_P_FOFF    (2048 + 6400000 + 40960)  // per-block partials: p1 12500*512 / p2 12500*256
#define WS_G_FOFF    (WS_P_FOFF + 6400000)     // bf16 G, rg-pair packed u32: 76.8M u32 = 307.2 MB
#define WS_NEED_BYTES 358572032ull

__device__ __forceinline__ u32 fbits(float f) { union { float f; u32 u; } v; v.f = f; return v.u; }
__device__ __forceinline__ float bits2f(u32 u) { union { u32 u; float f; } v; v.u = u; return v.f; }
// round-half-up bf16 pair pack: low16 = bf(a), high16 = bf(b)  (1 perm + 2 add)
__device__ __forceinline__ u32 pkbf(float a, float b) {
    return __builtin_amdgcn_perm(fbits(b) + 0x8000u, fbits(a) + 0x8000u, 0x07060302u);
}
__device__ __forceinline__ u16 f2bf1(float f) { return (u16)((fbits(f) + 0x8000u) >> 16); }
__device__ __forceinline__ float bf2f(u16 u) { return bits2f(((u32)u) << 16); }
__device__ __forceinline__ float softplusf(float x) {
    return fmaxf(x, 0.f) + log1pf(__expf(-fabsf(x)));
}
__device__ __forceinline__ float sigmoidf(float x) {
    return 1.f / (1.f + __expf(-x));
}

// Swizzle W (320x256 row-major fp32) -> wsW[kk][n][32] fragment-major bf16 (RNE, one-time)
__global__ void swizzleW(const float* __restrict__ W, u16* __restrict__ wsW) {
    int g = blockIdx.x * 256 + threadIdx.x;
    if (g >= KDIM * CDIM) return;
    int k = g >> 8, n = g & 255;
    u32 u = fbits(W[g]);
    u32 r = u + 0x7fffu + ((u >> 16) & 1u);
    wsW[((k >> 5) * 256 + n) * 32 + (k & 31)] = (u16)(r >> 16);
}

// sum(mask) -> ws[WS_CNT]
__global__ __launch_bounds__(256) void mask_cnt(const float* __restrict__ mask, float* __restrict__ ws) {
    int t = blockIdx.x * 256 + threadIdx.x;
    float s = 0.f;
    if (t < 37500) {
        const float* p = mask + (size_t)t * 16;
        #pragma unroll
        for (int i = 0; i < 4; i++) {
            float4 v = *(const float4*)(p + i * 4);
            s += (v.x + v.y) + (v.z + v.w);
        }
    }
    #pragma unroll
    for (int d = 1; d < 64; d <<= 1) s += __shfl_xor(s, d, 64);
    __shared__ float r[4];
    int l = threadIdx.x & 63, w = threadIdx.x >> 6;
    if (l == 0) r[w] = s;
    __syncthreads();
    if (threadIdx.x == 0) atomicAdd(&ws[WS_CNT], r[0] + r[1] + r[2] + r[3]);
}

// MODE 0: stats only (path-B pass 1)
// MODE 1: stats + store raw G blocked (path-A pass 1)
// MODE 2: recompute + BN + gate + consume (path-B pass 2)
template <int MODE>
__global__ __launch_bounds__(256, 3) void gemm_pass(
    const float* __restrict__ atom, const float* __restrict__ nbrf,
    const int* __restrict__ nbridx, const float* __restrict__ mask,
    const u16* __restrict__ wsW, float* __restrict__ ws)
{
    __shared__ __align__(16) char smem[RPB * A_PITCH];   // A-tile; MODE2 reuses as g16
    __shared__ float m_lds[RPB];
    __shared__ int   idx_lds[RPB];
    __shared__ float red[(MODE == 2) ? 4 : 1][128];

    const int tid = threadIdx.x;
    const int w = tid >> 6, l = tid & 63, l15 = l & 15, l4 = l >> 4;
    const int h32 = l >> 5, c32 = l & 31;
    const int blk = blockIdx.x;
    const int r0 = blk * RPB;
    const int wcol = w * 64;
    float* __restrict__ P = ws + WS_P_FOFF;

    if (tid < RPB) {
        m_lds[tid] = mask[r0 + tid];
        idx_lds[tid] = nbridx[r0 + tid];
    }
    __syncthreads();

    // ================= staging: wave w owns rows [12w, 12w+12) = atom blk*4+w =================
    // --- self features (wave-uniform atom): 32 float4 chunks, each half-wave writes 6 rows ---
    {
        float4 sv = *(const float4*)(atom + (size_t)(blk * 4 + w) * 128 + c32 * 4);
        uint2 p; p.x = pkbf(sv.x, sv.y); p.y = pkbf(sv.z, sv.w);
        #pragma unroll
        for (int jj = 0; jj < 6; ++jj) {
            int row = 12 * w + 6 * h32 + jj;
            *(uint2*)(smem + row * A_PITCH + c32 * 8) = p;
        }
    }
    // --- neighbor gather: 12 rows x 32 chunks, j = 2i + h32, c = l&31 ---
    {
        int nb[6];
        #pragma unroll
        for (int i = 0; i < 6; ++i) nb[i] = idx_lds[12 * w + 2 * i + h32];
        float4 v[6];
        #pragma unroll
        for (int i = 0; i < 6; ++i) v[i] = *(const float4*)(atom + (size_t)nb[i] * 128 + c32 * 4);
        #pragma unroll
        for (int i = 0; i < 6; ++i) {
            int row = 12 * w + 2 * i + h32;
            uint2 p; p.x = pkbf(v[i].x, v[i].y); p.y = pkbf(v[i].z, v[i].w);
            *(uint2*)(smem + row * A_PITCH + 256 + c32 * 8) = p;
        }
    }
    // --- nbr_fea: 12 rows x 16 chunks, fully contiguous per wave ---
    {
        const float* nf = nbrf + (size_t)(r0 + 12 * w) * 64;
        #pragma unroll
        for (int i = 0; i < 3; ++i) {
            int g = i * 64 + l;
            float4 v = *(const float4*)(nf + g * 4);
            int row = 12 * w + (g >> 4);
            int c = g & 15;
            uint2 p; p.x = pkbf(v.x, v.y); p.y = pkbf(v.z, v.w);
            *(uint2*)(smem + row * A_PITCH + 512 + c * 8) = p;
        }
    }
    __syncthreads();

    // ================= MFMA K-loop: 48x256 tile, wave w owns cols [64w,64w+64) =================
    f32x4 acc[3][4];
    #pragma unroll
    for (int rf = 0; rf < 3; rf++)
        #pragma unroll
        for (int cf = 0; cf < 4; cf++)
            acc[rf][cf] = (f32x4){0.f, 0.f, 0.f, 0.f};

    const char* Ab = smem + l15 * A_PITCH + l4 * 16;
    const char* Bb = (const char*)wsW + ((size_t)w * 4096 + l15 * 64 + l4 * 16);
    frag bcur[4], bnext[4];
    #pragma unroll
    for (int cf = 0; cf < 4; ++cf) bcur[cf] = *(const frag*)(Bb + cf * 1024);
    #pragma unroll
    for (int kk = 0; kk < KC; ++kk) {
        if (kk < KC - 1) {
            const char* Bn = Bb + (kk + 1) * 16384;
            #pragma unroll
            for (int cf = 0; cf < 4; ++cf) bnext[cf] = *(const frag*)(Bn + cf * 1024);
        }
        frag a[3];
        #pragma unroll
        for (int rf = 0; rf < 3; rf++)
            a[rf] = *(const frag*)(Ab + rf * 16 * A_PITCH + kk * 64);
        #pragma unroll
        for (int rf = 0; rf < 3; rf++)
            #pragma unroll
            for (int cf = 0; cf < 4; cf++)
                acc[rf][cf] = __builtin_amdgcn_mfma_f32_16x16x32_bf16(a[rf], bcur[cf], acc[rf][cf], 0, 0, 0);
        #pragma unroll
        for (int cf = 0; cf < 4; ++cf) bcur[cf] = bnext[cf];
    }

    if constexpr (MODE == 0 || MODE == 1) {
        // masked column sums / sumsq -> per-block partials
        #pragma unroll
        for (int cf = 0; cf < 4; cf++) {
            float s = 0.f, q = 0.f;
            #pragma unroll
            for (int rf = 0; rf < 3; rf++)
                #pragma unroll
                for (int rg = 0; rg < 4; rg++) {
                    int row = rf * 16 + l4 * 4 + rg;
                    float mv = m_lds[row];
                    float v = acc[rf][cf][rg];
                    s += mv * v; q += mv * v * v;
                }
            s += __shfl_xor(s, 16, 64); s += __shfl_xor(s, 32, 64);
            q += __shfl_xor(q, 16, 64); q += __shfl_xor(q, 32, 64);
            if (l4 == 0) {
                int col = wcol + cf * 16 + l15;
                P[(size_t)blk * 512 + col]       = s;
                P[(size_t)blk * 512 + 256 + col] = q;
            }
        }
        if constexpr (MODE == 1) {
            // store raw G, rg-pair-packed bf16, blocked layout: [atom][slot][lane]
            u32* gb = (u32*)(ws + WS_G_FOFF) + ((size_t)(blk * 4 + w) * 24) * 64 + l;
            #pragma unroll
            for (int rf = 0; rf < 3; rf++)
                #pragma unroll
                for (int cf = 0; cf < 4; cf++)
                    #pragma unroll
                    for (int p = 0; p < 2; p++)
                        gb[((rf * 4 + cf) * 2 + p) * 64] = pkbf(acc[rf][cf][2 * p], acc[rf][cf][2 * p + 1]);
        }
    } else {
        // ---- MODE 2: apply BN1, write normalized bf16 tile to LDS ----
        __syncthreads();   // all A-tile reads done before overwrite
        u16* g16 = (u16*)smem;
        #pragma unroll
        for (int cf = 0; cf < 4; cf++) {
            int col = wcol + cf * 16 + l15;
            float sc = ws[WS_SCALE1 + col];
            float sh = ws[WS_SHIFT1 + col];
            #pragma unroll
            for (int rf = 0; rf < 3; rf++)
                #pragma unroll
                for (int rg = 0; rg < 4; rg++) {
                    int row = rf * 16 + l4 * 4 + rg;
                    g16[row * 256 + col] = f2bf1(acc[rf][cf][rg] * sc + sh);
                }
        }
        __syncthreads();
        // ---- gated activation + reduce over M=12 -> nbr_sumed ----
        int h = tid >> 7;
        int c = tid & 127;
        float ns0 = 0.f, ns1 = 0.f;
        #pragma unroll
        for (int la2 = 0; la2 < 2; la2++) {
            int la = h * 2 + la2;
            float a_ns = 0.f;
            #pragma unroll
            for (int j = 0; j < 12; j++) {
                int row = la * 12 + j;
                float f = bf2f(g16[row * 256 + c]);
                float k = bf2f(g16[row * 256 + 128 + c]);
                a_ns += m_lds[row] * sigmoidf(f) * softplusf(k);
            }
            ws[WS_NBR + (blk * 4 + la) * 128 + c] = a_ns;
            if (la2 == 0) ns0 = a_ns; else ns1 = a_ns;
        }
        red[h][c]     = ns0 + ns1;
        red[2 + h][c] = ns0 * ns0 + ns1 * ns1;
        __syncthreads();
        if (tid < 128) {
            P[(size_t)blk * 256 + tid]       = red[0][tid] + red[1][tid];
            P[(size_t)blk * 256 + 128 + tid] = red[2][tid] + red[3][tid];
        }
    }
}

// path-A pass 2: load blocked G, BN1 + gate + reduce (no staging, no MFMA)
__global__ __launch_bounds__(256) void pass2_load(
    const float* __restrict__ ws_ro, const float* __restrict__ mask, float* __restrict__ ws)
{
    __shared__ u16 g16[RPB * 256];
    __shared__ float m_lds[RPB];
    __shared__ float red[4][128];

    const int tid = threadIdx.x;
    const int w = tid >> 6, l = tid & 63, l15 = l & 15, l4 = l >> 4;
    const int blk = blockIdx.x;
    float* __restrict__ P = ws + WS_P_FOFF;

    if (tid < RPB) m_lds[tid] = mask[blk * RPB + tid];

    const u32* gb = (const u32*)(ws_ro + WS_G_FOFF) + ((size_t)(blk * 4 + w) * 24) * 64 + l;
    u32 v[24];
    #pragma unroll
    for (int s = 0; s < 24; s++) v[s] = gb[s * 64];

    float sc[4], sh[4];
    #pragma unroll
    for (int cf = 0; cf < 4; cf++) {
        int col = w * 64 + cf * 16 + l15;
        sc[cf] = ws_ro[WS_SCALE1 + col];
        sh[cf] = ws_ro[WS_SHIFT1 + col];
    }
    #pragma unroll
    for (int rf = 0; rf < 3; rf++)
        #pragma unroll
        for (int cf = 0; cf < 4; cf++)
            #pragma unroll
            for (int p = 0; p < 2; p++) {
                u32 u = v[(rf * 4 + cf) * 2 + p];
                float flo = bits2f(u << 16)        * sc[cf] + sh[cf];
                float fhi = bits2f(u & 0xffff0000u) * sc[cf] + sh[cf];
                int row = rf * 16 + l4 * 4 + 2 * p;
                int col = w * 64 + cf * 16 + l15;
                g16[row * 256 + col]       = f2bf1(flo);
                g16[(row + 1) * 256 + col] = f2bf1(fhi);
            }
    __syncthreads();

    int h = tid >> 7;
    int c = tid & 127;
    float ns0 = 0.f, ns1 = 0.f;
    #pragma unroll
    for (int la2 = 0; la2 < 2; la2++) {
        int la = h * 2 + la2;
        float a_ns = 0.f;
        #pragma unroll
        for (int j = 0; j < 12; j++) {
            int row = la * 12 + j;
            float f = bf2f(g16[row * 256 + c]);
            float k = bf2f(g16[row * 256 + 128 + c]);
            a_ns += m_lds[row] * sigmoidf(f) * softplusf(k);
        }
        ws[WS_NBR + (blk * 4 + la) * 128 + c] = a_ns;
        if (la2 == 0) ns0 = a_ns; else ns1 = a_ns;
    }
    red[h][c]     = ns0 + ns1;
    red[2 + h][c] = ns0 * ns0 + ns1 * ns1;
    __syncthreads();
    if (tid < 128) {
        P[(size_t)blk * 256 + tid]       = red[0][tid] + red[1][tid];
        P[(size_t)blk * 256 + 128 + tid] = red[2][tid] + red[3][tid];
    }
}

// reduce P1[12500][512] over blocks -> ws[WS_SUM1..] ; grid 250
__global__ __launch_bounds__(256) void red1(const float* __restrict__ ws_ro, float* __restrict__ ws) {
    const float* P = ws_ro + WS_P_FOFF;
    int c = (blockIdx.x & 1) * 256 + threadIdx.x;
    int s = blockIdx.x >> 1;
    const float* p = P + (size_t)s * 100 * 512 + c;
    float a = 0.f;
    #pragma unroll 4
    for (int r = 0; r < 100; r++) a += p[(size_t)r * 512];
    atomicAdd(&ws[WS_SUM1 + c], a);
}

// reduce P2[12500][256] over blocks -> ws[WS_SUM2..] ; grid 125
__global__ __launch_bounds__(256) void red2(const float* __restrict__ ws_ro, float* __restrict__ ws) {
    const float* P = ws_ro + WS_P_FOFF;
    int s = blockIdx.x;
    const float* p = P + (size_t)s * 100 * 256 + threadIdx.x;
    float a = 0.f;
    #pragma unroll 4
    for (int r = 0; r < 100; r++) a += p[(size_t)r * 256];
    atomicAdd(&ws[WS_SUM2 + threadIdx.x], a);
}

__global__ void finalize1(float* __restrict__ ws, const float* __restrict__ g1, const float* __restrict__ b1) {
    int c = threadIdx.x;  // 256
    float cnt = ws[WS_CNT];
    float mean = ws[WS_SUM1 + c] / cnt;
    float var  = ws[WS_SUMSQ1 + c] / cnt - mean * mean;
    float sc = g1[c] * rsqrtf(var + EPSV);
    ws[WS_SCALE1 + c] = sc;
    ws[WS_SHIFT1 + c] = b1[c] - mean * sc;
}

__global__ void finalize2(float* __restrict__ ws, const float* __restrict__ g2, const float* __restrict__ b2) {
    int c = threadIdx.x;  // 128
    float inv = 1.f / (float)N_ATOM;
    float mean = ws[WS_SUM2 + c] * inv;
    float var  = ws[WS_SUMSQ2 + c] * inv - mean * mean;
    float sc = g2[c] * rsqrtf(var + EPSV);
    ws[WS_SCALE2 + c] = sc;
    ws[WS_SHIFT2 + c] = b2[c] - mean * sc;
}

__global__ __launch_bounds__(256) void out_kernel(
    const float* __restrict__ atom, const float* __restrict__ ws, float* __restrict__ out)
{
    int g = blockIdx.x * 256 + threadIdx.x;
    if (g >= N_ATOM * 32) return;
    int i = g >> 5, c4 = (g & 31) * 4;
    float4 av = *(const float4*)(atom + i * 128 + c4);
    float4 nv = *(const float4*)(ws + WS_NBR + i * 128 + c4);
    float4 sc = *(const float4*)(ws + WS_SCALE2 + c4);
    float4 sh = *(const float4*)(ws + WS_SHIFT2 + c4);
    float4 ov;
    ov.x = softplusf(av.x + nv.x * sc.x + sh.x);
    ov.y = softplusf(av.y + nv.y * sc.y + sh.y);
    ov.z = softplusf(av.z + nv.z * sc.z + sh.z);
    ov.w = softplusf(av.w + nv.w * sc.w + sh.w);
    *(float4*)(out + i * 128 + c4) = ov;
}

extern "C" void kernel_launch(void* const* d_in, const int* in_sizes, int n_in,
                              void* d_out, int out_size, void* d_ws, size_t ws_size,
                              hipStream_t stream) {
    (void)in_sizes; (void)n_in; (void)out_size;
    const float* atom = (const float*)d_in[0];
    const float* nbrf = (const float*)d_in[1];
    const int*   nidx = (const int*)d_in[2];
    const float* mask = (const float*)d_in[3];
    const float* W    = (const float*)d_in[4];
    // d_in[5] = b_fc: zeros AND cancels exactly through BN1 for masked rows; unused
    const float* g1 = (const float*)d_in[6];
    const float* b1 = (const float*)d_in[7];
    const float* g2 = (const float*)d_in[8];
    const float* b2 = (const float*)d_in[9];
    float* ws  = (float*)d_ws;
    u16*  wsW  = (u16*)((char*)d_ws + (size_t)WS_W_FOFF * 4);
    float* out = (float*)d_out;
    const bool bigws = (ws_size >= WS_NEED_BYTES);

    hipMemsetAsync(d_ws, 0, WS_STATS_END * 4, stream);
    swizzleW<<<(KDIM * CDIM + 255) / 256, 256, 0, stream>>>(W, wsW);
    mask_cnt<<<147, 256, 0, stream>>>(mask, ws);
    if (bigws) {
        gemm_pass<1><<<NBLK, 256, 0, stream>>>(atom, nbrf, nidx, mask, wsW, ws);
        red1<<<250, 256, 0, stream>>>(ws, ws);
        finalize1<<<1, 256, 0, stream>>>(ws, g1, b1);
        pass2_load<<<NBLK, 256, 0, stream>>>(ws, mask, ws);
    } else {
        gemm_pass<0><<<NBLK, 256, 0, stream>>>(atom, nbrf, nidx, mask, wsW, ws);
        red1<<<250, 256, 0, stream>>>(ws, ws);
        finalize1<<<1, 256, 0, stream>>>(ws, g1, b1);
        gemm_pass<2><<<NBLK, 256, 0, stream>>>(atom, nbrf, nidx, mask, wsW, ws);
    }
    red2<<<125, 256, 0, stream>>>(ws, ws);
    finalize2<<<1, 128, 0, stream>>>(ws, g2, b2);
    out_kernel<<<(N_ATOM * 32 + 255) / 256, 256, 0, stream>>>(atom, ws, out);
}